// Round 1
// baseline (190.660 us; speedup 1.0000x reference)
//
#include <hip/hip_runtime.h>
#include <hip/hip_bf16.h>

#define BB 4
#define TT 4096
#define DM 1024
#define DK 64

using f32x4  = __attribute__((ext_vector_type(4))) float;
using bf16x8 = __attribute__((ext_vector_type(8))) short;

__device__ __forceinline__ short f2bf(float f) {
    __hip_bfloat16 h = __float2bfloat16(f);
    return __builtin_bit_cast(short, h);
}

// ---------------- Kernel 0: pack Wq|Wk|Wv (f32 [1024][64]) -> Wt bf16 [192][1024]
__global__ __launch_bounds__(256) void wt_kernel(const float* __restrict__ Wq,
                                                 const float* __restrict__ Wk,
                                                 const float* __restrict__ Wv,
                                                 short* __restrict__ Wt) {
    int idx = blockIdx.x * 256 + threadIdx.x;     // over 192*1024
    if (idx >= 192 * 1024) return;
    int n = idx >> 10;        // 0..191  (output row = W column)
    int m = idx & 1023;       // 0..1023 (k)
    const float* W = (n < 64) ? Wq : (n < 128) ? Wk : Wv;
    int c = n & 63;
    Wt[idx] = f2bf(W[m * 64 + c]);
}

// ---------------- Kernel 1: QKV projection (MFMA bf16) + RoPE, write q,k,[Vt transposed]
// grid: 256 blocks x 256 threads. Each wave: 16 M-rows, all 192 N-cols.
__global__ __launch_bounds__(256) void proj_rope(const float* __restrict__ x,     // [16384][1024]
                                                 const float* __restrict__ freqs, // [4096][32][2]
                                                 const short* __restrict__ Wt,    // [192][1024] bf16
                                                 short* __restrict__ q,           // [16384][64] bf16
                                                 short* __restrict__ k,           // [16384][64] bf16
                                                 short* __restrict__ vt)          // [4][64][4096] bf16
{
    int w  = threadIdx.x >> 6;
    int l  = threadIdx.x & 63;
    int lr = l & 15;
    int lg = l >> 4;
    int rowbase = blockIdx.x * 64 + w * 16;

    f32x4 acc[12];
#pragma unroll
    for (int i = 0; i < 12; ++i) acc[i] = (f32x4){0.f, 0.f, 0.f, 0.f};

    const float* xrow = x + (size_t)(rowbase + lr) * DM;

    for (int kk = 0; kk < DM; kk += 32) {
        // A fragment: x[rowbase+lr][kk + 8*lg .. +7], cvt f32->bf16
        f32x4 xa = *(const f32x4*)(xrow + kk + 8 * lg);
        f32x4 xb = *(const f32x4*)(xrow + kk + 8 * lg + 4);
        bf16x8 af;
#pragma unroll
        for (int j = 0; j < 4; ++j) { af[j] = f2bf(xa[j]); af[4 + j] = f2bf(xb[j]); }
#pragma unroll
        for (int nt = 0; nt < 12; ++nt) {
            bf16x8 bfr = *(const bf16x8*)(Wt + (size_t)(nt * 16 + lr) * DM + kk + 8 * lg);
            acc[nt] = __builtin_amdgcn_mfma_f32_16x16x32_bf16(af, bfr, acc[nt], 0, 0, 0);
        }
    }

    // Epilogue: C layout col = lane&15 (n within tile), row = lg*4 + r (M)
#pragma unroll
    for (int r = 0; r < 4; ++r) {
        int t  = rowbase + lg * 4 + r;     // global M row
        int tt = t & (TT - 1);
        int b  = t >> 12;
#pragma unroll
        for (int nt = 0; nt < 4; ++nt) {
            int c = nt * 16 + lr;          // column within D_K (0..63)
            float qe = acc[nt][r];
            float ke = acc[nt + 4][r];
            float ve = acc[nt + 8][r];
            float qp = __shfl_xor(qe, 1);  // partner (even<->odd pair)
            float kp = __shfl_xor(ke, 1);
            float2 f = ((const float2*)freqs)[(size_t)tt * 32 + (c >> 1)]; // (cos, sin)
            float sgn = (c & 1) ? f.y : -f.y;
            float qo = qe * f.x + qp * sgn;  // even: e*cos - o*sin ; odd: o*cos + e*sin
            float ko = ke * f.x + kp * sgn;
            q[(size_t)t * DK + c] = f2bf(qo);
            k[(size_t)t * DK + c] = f2bf(ko);
            vt[((size_t)b * DK + c) * TT + tt] = f2bf(ve);
        }
    }
}

// ---------------- Kernel 2: causal flash attention, bf16 MFMA
// grid: (T/64, B) x 256 threads. Wave w handles q rows [qb + w*16, +16).
__global__ __launch_bounds__(256) void attn_kernel(const short* __restrict__ q,
                                                   const short* __restrict__ k,
                                                   const short* __restrict__ vt,
                                                   float* __restrict__ out)
{
    __shared__ short pbuf[4][16][32];

    int w  = threadIdx.x >> 6;
    int l  = threadIdx.x & 63;
    int lr = l & 15;
    int lg = l >> 4;
    int b  = blockIdx.y;
    int qb = blockIdx.x * 64;
    int qrow_wave = qb + w * 16;

    const short* qB = q  + (size_t)b * TT * DK;
    const short* kB = k  + (size_t)b * TT * DK;
    const short* vB = vt + (size_t)b * DK * TT;

    bf16x8 qf0 = *(const bf16x8*)(qB + (size_t)(qrow_wave + lr) * DK + 8 * lg);
    bf16x8 qf1 = *(const bf16x8*)(qB + (size_t)(qrow_wave + lr) * DK + 32 + 8 * lg);

    f32x4 of[4];
#pragma unroll
    for (int i = 0; i < 4; ++i) of[i] = (f32x4){0.f, 0.f, 0.f, 0.f};
    float m[4], lsum[4];
#pragma unroll
    for (int r = 0; r < 4; ++r) { m[r] = -INFINITY; lsum[r] = 0.f; }

    int kv_end = qb + 64;
    for (int kv = 0; kv < kv_end; kv += 32) {
        bf16x8 kf00 = *(const bf16x8*)(kB + (size_t)(kv + lr) * DK + 8 * lg);
        bf16x8 kf01 = *(const bf16x8*)(kB + (size_t)(kv + lr) * DK + 32 + 8 * lg);
        bf16x8 kf10 = *(const bf16x8*)(kB + (size_t)(kv + 16 + lr) * DK + 8 * lg);
        bf16x8 kf11 = *(const bf16x8*)(kB + (size_t)(kv + 16 + lr) * DK + 32 + 8 * lg);

        f32x4 s0 = (f32x4){0.f, 0.f, 0.f, 0.f};
        f32x4 s1 = (f32x4){0.f, 0.f, 0.f, 0.f};
        s0 = __builtin_amdgcn_mfma_f32_16x16x32_bf16(qf0, kf00, s0, 0, 0, 0);
        s0 = __builtin_amdgcn_mfma_f32_16x16x32_bf16(qf1, kf01, s0, 0, 0, 0);
        s1 = __builtin_amdgcn_mfma_f32_16x16x32_bf16(qf0, kf10, s1, 0, 0, 0);
        s1 = __builtin_amdgcn_mfma_f32_16x16x32_bf16(qf1, kf11, s1, 0, 0, 0);

        float pm[4];
#pragma unroll
        for (int r = 0; r < 4; ++r) {
            int qg = qrow_wave + lg * 4 + r;
            float a0 = (kv + lr      <= qg) ? s0[r] * 0.125f : -INFINITY;
            float a1 = (kv + 16 + lr <= qg) ? s1[r] * 0.125f : -INFINITY;
            s0[r] = a0; s1[r] = a1;
            float mx = fmaxf(a0, a1);
            mx = fmaxf(mx, __shfl_xor(mx, 1));
            mx = fmaxf(mx, __shfl_xor(mx, 2));
            mx = fmaxf(mx, __shfl_xor(mx, 4));
            mx = fmaxf(mx, __shfl_xor(mx, 8));
            pm[r] = mx;
        }
#pragma unroll
        for (int r = 0; r < 4; ++r) {
            float mn = fmaxf(m[r], pm[r]);            // finite after first tile (col 0 always valid)
            float alpha = __expf(m[r] - mn);          // first iter: exp(-inf) = 0
            float p0 = __expf(s0[r] - mn);            // masked: exp(-inf) = 0
            float p1 = __expf(s1[r] - mn);
            float ps = p0 + p1;
            ps += __shfl_xor(ps, 1);
            ps += __shfl_xor(ps, 2);
            ps += __shfl_xor(ps, 4);
            ps += __shfl_xor(ps, 8);
            lsum[r] = lsum[r] * alpha + ps;
            m[r] = mn;
#pragma unroll
            for (int dt = 0; dt < 4; ++dt) of[dt][r] *= alpha;
            pbuf[w][lg * 4 + r][lr]      = f2bf(p0);
            pbuf[w][lg * 4 + r][16 + lr] = f2bf(p1);
        }
        // PV: A = P (16x32) from LDS, B = Vt slice (contiguous per lane)
        bf16x8 pa = *(const bf16x8*)(&pbuf[w][lr][8 * lg]);
#pragma unroll
        for (int dt = 0; dt < 4; ++dt) {
            bf16x8 vf = *(const bf16x8*)(vB + (size_t)(dt * 16 + lr) * TT + kv + 8 * lg);
            of[dt] = __builtin_amdgcn_mfma_f32_16x16x32_bf16(pa, vf, of[dt], 0, 0, 0);
        }
    }

#pragma unroll
    for (int r = 0; r < 4; ++r) {
        float inv = 1.0f / lsum[r];
        int t = qrow_wave + lg * 4 + r;
        float* orow = out + ((size_t)b * TT + t) * DK;
#pragma unroll
        for (int dt = 0; dt < 4; ++dt) orow[dt * 16 + lr] = of[dt][r] * inv;
    }
}

extern "C" void kernel_launch(void* const* d_in, const int* in_sizes, int n_in,
                              void* d_out, int out_size, void* d_ws, size_t ws_size,
                              hipStream_t stream) {
    const float* x     = (const float*)d_in[0];
    const float* freqs = (const float*)d_in[1];
    const float* Wq    = (const float*)d_in[2];
    const float* Wk    = (const float*)d_in[3];
    const float* Wv    = (const float*)d_in[4];
    float* out = (float*)d_out;

    char* ws = (char*)d_ws;
    short* Wt  = (short*)ws;                               // 192*1024*2 = 393216 B
    short* qb  = (short*)(ws + 393216);                    // 16384*64*2 = 2 MB
    short* kb  = (short*)(ws + 393216 + 2097152);          // 2 MB
    short* vtb = (short*)(ws + 393216 + 2 * 2097152);      // 2 MB (transposed V)

    hipLaunchKernelGGL(wt_kernel, dim3(768), dim3(256), 0, stream, Wq, Wk, Wv, Wt);
    hipLaunchKernelGGL(proj_rope, dim3(256), dim3(256), 0, stream, x, freqs, Wt, qb, kb, vtb);
    hipLaunchKernelGGL(attn_kernel, dim3(TT / 64, BB), dim3(256), 0, stream, qb, kb, vtb, out);
}

// Round 2
// 168.569 us; speedup vs baseline: 1.1311x; 1.1311x over previous
//
#include <hip/hip_runtime.h>
#include <hip/hip_bf16.h>

#define BB 4
#define TT 4096
#define DM 1024
#define DK 64

using f32x4  = __attribute__((ext_vector_type(4))) float;
using bf16x8 = __attribute__((ext_vector_type(8))) short;

__device__ __forceinline__ short f2bf(float f) {
    __hip_bfloat16 h = __float2bfloat16(f);
    return __builtin_bit_cast(short, h);
}

// ---------------- Kernel 0: pack Wq|Wk|Wv (f32 [1024][64]) -> Wt bf16 [192][1024]
__global__ __launch_bounds__(256) void wt_kernel(const float* __restrict__ Wq,
                                                 const float* __restrict__ Wk,
                                                 const float* __restrict__ Wv,
                                                 short* __restrict__ Wt) {
    int idx = blockIdx.x * 256 + threadIdx.x;     // over 192*1024
    if (idx >= 192 * 1024) return;
    int n = idx >> 10;        // 0..191  (output row = W column)
    int m = idx & 1023;       // 0..1023 (k)
    const float* W = (n < 64) ? Wq : (n < 128) ? Wk : Wv;
    int c = n & 63;
    Wt[idx] = f2bf(W[m * 64 + c]);
}

// ---------------- Kernel 1: QKV projection (MFMA bf16) + RoPE
// grid: (256 row-blocks, 3 outputs) x 256 threads. Wave: 16 rows x 64 cols of ONE output.
__global__ __launch_bounds__(256) void proj_rope(const float* __restrict__ x,     // [16384][1024]
                                                 const float* __restrict__ freqs, // [4096][32][2]
                                                 const short* __restrict__ Wt,    // [192][1024] bf16
                                                 short* __restrict__ q,           // [16384][64] bf16
                                                 short* __restrict__ k,           // [16384][64] bf16
                                                 short* __restrict__ vt)          // [4][64][4096] bf16
{
    __shared__ short vs[64][64];

    int which = blockIdx.y;                 // 0=q, 1=k, 2=v
    int w  = threadIdx.x >> 6;
    int l  = threadIdx.x & 63;
    int lr = l & 15;
    int lg = l >> 4;
    int rowbase = blockIdx.x * 64 + w * 16;

    f32x4 acc[4];
#pragma unroll
    for (int i = 0; i < 4; ++i) acc[i] = (f32x4){0.f, 0.f, 0.f, 0.f};

    const float* xrow = x + (size_t)(rowbase + lr) * DM;
    const short* Wb   = Wt + (size_t)which * 64 * DM;

    for (int kk = 0; kk < DM; kk += 32) {
        f32x4 xa = *(const f32x4*)(xrow + kk + 8 * lg);
        f32x4 xb = *(const f32x4*)(xrow + kk + 8 * lg + 4);
        bf16x8 af;
#pragma unroll
        for (int j = 0; j < 4; ++j) { af[j] = f2bf(xa[j]); af[4 + j] = f2bf(xb[j]); }
#pragma unroll
        for (int nt = 0; nt < 4; ++nt) {
            bf16x8 bfr = *(const bf16x8*)(Wb + (size_t)(nt * 16 + lr) * DM + kk + 8 * lg);
            acc[nt] = __builtin_amdgcn_mfma_f32_16x16x32_bf16(af, bfr, acc[nt], 0, 0, 0);
        }
    }

    if (which == 2) {
        // V: stage block's 64x64 tile in LDS, write transposed coalesced (bf16x8 along t)
#pragma unroll
        for (int r = 0; r < 4; ++r)
#pragma unroll
            for (int nt = 0; nt < 4; ++nt)
                vs[w * 16 + lg * 4 + r][nt * 16 + lr] = f2bf(acc[nt][r]);
        __syncthreads();
        int b   = blockIdx.x >> 6;              // 64 rows per block, 64 blocks per batch
        int tt0 = (blockIdx.x & 63) * 64;
        for (int task = threadIdx.x; task < 512; task += 256) {
            int c  = task & 63;
            int tg = task >> 6;
            bf16x8 val;
#pragma unroll
            for (int j = 0; j < 8; ++j) val[j] = vs[tg * 8 + j][c];
            *(bf16x8*)(vt + ((size_t)b * DK + c) * TT + tt0 + tg * 8) = val;
        }
    } else {
        short* dst = which ? k : q;
#pragma unroll
        for (int r = 0; r < 4; ++r) {
            int t  = rowbase + lg * 4 + r;
            int tt = t & (TT - 1);
#pragma unroll
            for (int nt = 0; nt < 4; ++nt) {
                int c = nt * 16 + lr;
                float e = acc[nt][r];
                float p = __shfl_xor(e, 1);
                float2 f = ((const float2*)freqs)[(size_t)tt * 32 + (c >> 1)];
                float sgn = (c & 1) ? f.y : -f.y;
                dst[(size_t)t * DK + c] = f2bf(e * f.x + p * sgn);
            }
        }
    }
}

// ---------------- Kernel 2: causal flash attention, intra-block KV-split (8 waves / q-tile)
// grid: (T/16, B) x 512 threads. All 8 waves share the same 16 q rows; wave w takes
// kv tiles {w, w+8, ...}; partial (m,l,o) merged in LDS at the end.
__global__ __launch_bounds__(512, 4) void attn_kernel(const short* __restrict__ q,
                                                      const short* __restrict__ k,
                                                      const short* __restrict__ vt,
                                                      float* __restrict__ out)
{
    __shared__ __align__(16) char smem[33792];
    short* pbuf = (short*)smem;             // [8][16][40] during kv loop
    float* po   = (float*)smem;             // [8][16][64] after barrier (overlaps pbuf)
    float* pmv  = (float*)(smem + 32768);   // [8][16]
    float* plv  = (float*)(smem + 33280);   // [8][16]

    int w  = threadIdx.x >> 6;
    int l  = threadIdx.x & 63;
    int lr = l & 15;
    int lg = l >> 4;
    int b  = blockIdx.y;
    int qt = (gridDim.x - 1) - blockIdx.x;  // heavy q-tiles launch first
    int q0 = qt * 16;

    const short* qB = q  + (size_t)b * TT * DK;
    const short* kB = k  + (size_t)b * TT * DK;
    const short* vB = vt + (size_t)b * DK * TT;

    bf16x8 qf0 = *(const bf16x8*)(qB + (size_t)(q0 + lr) * DK + 8 * lg);
    bf16x8 qf1 = *(const bf16x8*)(qB + (size_t)(q0 + lr) * DK + 32 + 8 * lg);

    f32x4 of[4];
#pragma unroll
    for (int i = 0; i < 4; ++i) of[i] = (f32x4){0.f, 0.f, 0.f, 0.f};
    float m[4], lsum[4];
#pragma unroll
    for (int r = 0; r < 4; ++r) { m[r] = -INFINITY; lsum[r] = 0.f; }

    int ntiles = (q0 + 47) >> 5;            // ceil((q0+16)/32)
    short* mypb = pbuf + w * 16 * 40;

    for (int j = w; j < ntiles; j += 8) {
        int kv = j << 5;
        bf16x8 kf00 = *(const bf16x8*)(kB + (size_t)(kv + lr) * DK + 8 * lg);
        bf16x8 kf01 = *(const bf16x8*)(kB + (size_t)(kv + lr) * DK + 32 + 8 * lg);
        bf16x8 kf10 = *(const bf16x8*)(kB + (size_t)(kv + 16 + lr) * DK + 8 * lg);
        bf16x8 kf11 = *(const bf16x8*)(kB + (size_t)(kv + 16 + lr) * DK + 32 + 8 * lg);

        f32x4 s0 = (f32x4){0.f, 0.f, 0.f, 0.f};
        f32x4 s1 = (f32x4){0.f, 0.f, 0.f, 0.f};
        s0 = __builtin_amdgcn_mfma_f32_16x16x32_bf16(qf0, kf00, s0, 0, 0, 0);
        s0 = __builtin_amdgcn_mfma_f32_16x16x32_bf16(qf1, kf01, s0, 0, 0, 0);
        s1 = __builtin_amdgcn_mfma_f32_16x16x32_bf16(qf0, kf10, s1, 0, 0, 0);
        s1 = __builtin_amdgcn_mfma_f32_16x16x32_bf16(qf1, kf11, s1, 0, 0, 0);

        float pm[4];
#pragma unroll
        for (int r = 0; r < 4; ++r) {
            int qg = q0 + lg * 4 + r;
            float a0 = (kv + lr      <= qg) ? s0[r] * 0.125f : -INFINITY;
            float a1 = (kv + 16 + lr <= qg) ? s1[r] * 0.125f : -INFINITY;
            s0[r] = a0; s1[r] = a1;
            float mx = fmaxf(a0, a1);
            mx = fmaxf(mx, __shfl_xor(mx, 1));
            mx = fmaxf(mx, __shfl_xor(mx, 2));
            mx = fmaxf(mx, __shfl_xor(mx, 4));
            mx = fmaxf(mx, __shfl_xor(mx, 8));
            pm[r] = mx;                     // finite: col kv (<= q0) always unmasked
        }
#pragma unroll
        for (int r = 0; r < 4; ++r) {
            float mn = fmaxf(m[r], pm[r]);
            float alpha = __expf(m[r] - mn);   // first tile: exp(-inf - finite) = 0
            float p0 = __expf(s0[r] - mn);
            float p1 = __expf(s1[r] - mn);
            float ps = p0 + p1;
            ps += __shfl_xor(ps, 1);
            ps += __shfl_xor(ps, 2);
            ps += __shfl_xor(ps, 4);
            ps += __shfl_xor(ps, 8);
            lsum[r] = lsum[r] * alpha + ps;
            m[r] = mn;
#pragma unroll
            for (int dt = 0; dt < 4; ++dt) of[dt][r] *= alpha;
            mypb[(lg * 4 + r) * 40 + lr]      = f2bf(p0);
            mypb[(lg * 4 + r) * 40 + 16 + lr] = f2bf(p1);
        }
        // PV: A = P (16x32) from LDS (stride 40 shorts -> 2-way banks, free)
        bf16x8 pa = *(const bf16x8*)(mypb + lr * 40 + 8 * lg);
#pragma unroll
        for (int dt = 0; dt < 4; ++dt) {
            bf16x8 vf = *(const bf16x8*)(vB + (size_t)(dt * 16 + lr) * TT + kv + 8 * lg);
            of[dt] = __builtin_amdgcn_mfma_f32_16x16x32_bf16(pa, vf, of[dt], 0, 0, 0);
        }
    }

    // ---- merge the 8 waves' partials
    __syncthreads();                        // everyone done with pbuf
#pragma unroll
    for (int r = 0; r < 4; ++r) {
        int row = lg * 4 + r;
#pragma unroll
        for (int dt = 0; dt < 4; ++dt) po[(w * 16 + row) * 64 + dt * 16 + lr] = of[dt][r];
        if (lr == 0) { pmv[w * 16 + row] = m[r]; plv[w * 16 + row] = lsum[r]; }
    }
    __syncthreads();
    for (int e = threadIdx.x; e < 1024; e += 512) {
        int row = e >> 6, col = e & 63;
        float M = -INFINITY;
#pragma unroll
        for (int w2 = 0; w2 < 8; ++w2) M = fmaxf(M, pmv[w2 * 16 + row]);
        float L = 0.f, o = 0.f;
#pragma unroll
        for (int w2 = 0; w2 < 8; ++w2) {
            float sc = __expf(pmv[w2 * 16 + row] - M);   // idle wave: exp(-inf)=0
            L += plv[w2 * 16 + row] * sc;
            o += po[(w2 * 16 + row) * 64 + col] * sc;
        }
        out[((size_t)b * TT + q0 + row) * DK + col] = o / L;
    }
}

extern "C" void kernel_launch(void* const* d_in, const int* in_sizes, int n_in,
                              void* d_out, int out_size, void* d_ws, size_t ws_size,
                              hipStream_t stream) {
    const float* x     = (const float*)d_in[0];
    const float* freqs = (const float*)d_in[1];
    const float* Wq    = (const float*)d_in[2];
    const float* Wk    = (const float*)d_in[3];
    const float* Wv    = (const float*)d_in[4];
    float* out = (float*)d_out;

    char* ws = (char*)d_ws;
    short* Wt  = (short*)ws;                               // 192*1024*2 = 393216 B
    short* qb  = (short*)(ws + 393216);                    // 16384*64*2 = 2 MB
    short* kb  = (short*)(ws + 393216 + 2097152);          // 2 MB
    short* vtb = (short*)(ws + 393216 + 2 * 2097152);      // 2 MB (transposed V)

    hipLaunchKernelGGL(wt_kernel, dim3(768), dim3(256), 0, stream, Wq, Wk, Wv, Wt);
    hipLaunchKernelGGL(proj_rope, dim3(256, 3), dim3(256), 0, stream, x, freqs, Wt, qb, kb, vtb);
    hipLaunchKernelGGL(attn_kernel, dim3(TT / 16, BB), dim3(512), 0, stream, qb, kb, vtb, out);
}

// Round 3
// 119.031 us; speedup vs baseline: 1.6018x; 1.4162x over previous
//
#include <hip/hip_runtime.h>
#include <hip/hip_bf16.h>

#define BB 4
#define TT 4096
#define DM 1024
#define DK 64

using f32x4  = __attribute__((ext_vector_type(4))) float;
using bf16x8 = __attribute__((ext_vector_type(8))) short;

__device__ __forceinline__ short f2bf(float f) {
    __hip_bfloat16 h = __float2bfloat16(f);
    return __builtin_bit_cast(short, h);
}

// ---------------- Kernel 0: pack Wq|Wk|Wv (f32 [1024][64]) -> Wt bf16 [192][1024]
__global__ __launch_bounds__(256) void wt_kernel(const float* __restrict__ Wq,
                                                 const float* __restrict__ Wk,
                                                 const float* __restrict__ Wv,
                                                 short* __restrict__ Wt) {
    int idx = blockIdx.x * 256 + threadIdx.x;
    if (idx >= 192 * 1024) return;
    int n = idx >> 10;
    int m = idx & 1023;
    const float* W = (n < 64) ? Wq : (n < 128) ? Wk : Wv;
    int c = n & 63;
    Wt[idx] = f2bf(W[m * 64 + c]);
}

// ---------------- Kernel 1: QKV projection, single-pass (x read once), 2-way K-split
// grid: 256 blocks x 512 threads (8 waves). Waves w and w+4: same 16 rows, halves of K.
__global__ __launch_bounds__(512, 4) void proj_rope(const float* __restrict__ x,
                                                    const float* __restrict__ freqs,
                                                    const short* __restrict__ Wt,
                                                    short* __restrict__ q,
                                                    short* __restrict__ k,
                                                    short* __restrict__ vt)
{
    __shared__ float accbuf[4][12][16][16];   // 48 KB
    __shared__ short vs[64][64];              // 8 KB

    int w    = threadIdx.x >> 6;
    int l    = threadIdx.x & 63;
    int lr   = l & 15;
    int lg   = l >> 4;
    int half = w >> 2;
    int wq   = w & 3;
    int rowbase = blockIdx.x * 64 + wq * 16;

    f32x4 acc[12];
#pragma unroll
    for (int i = 0; i < 12; ++i) acc[i] = (f32x4){0.f, 0.f, 0.f, 0.f};

    const float* xrow = x + (size_t)(rowbase + lr) * DM + (half << 9);

    for (int kk = 0; kk < 512; kk += 32) {
        f32x4 xa = *(const f32x4*)(xrow + kk + 8 * lg);
        f32x4 xb = *(const f32x4*)(xrow + kk + 8 * lg + 4);
        bf16x8 af;
#pragma unroll
        for (int j = 0; j < 4; ++j) { af[j] = f2bf(xa[j]); af[4 + j] = f2bf(xb[j]); }
#pragma unroll
        for (int nt = 0; nt < 12; ++nt) {
            bf16x8 bfr = *(const bf16x8*)(Wt + (size_t)(nt * 16 + lr) * DM + (half << 9) + kk + 8 * lg);
            acc[nt] = __builtin_amdgcn_mfma_f32_16x16x32_bf16(af, bfr, acc[nt], 0, 0, 0);
        }
    }

    if (half == 1) {
#pragma unroll
        for (int nt = 0; nt < 12; ++nt)
#pragma unroll
            for (int r = 0; r < 4; ++r)
                accbuf[wq][nt][lg * 4 + r][lr] = acc[nt][r];
    }
    __syncthreads();
    if (half == 0) {
#pragma unroll
        for (int nt = 0; nt < 12; ++nt)
#pragma unroll
            for (int r = 0; r < 4; ++r)
                acc[nt][r] += accbuf[wq][nt][lg * 4 + r][lr];

#pragma unroll
        for (int r = 0; r < 4; ++r) {
            int t  = rowbase + lg * 4 + r;
            int tt = t & (TT - 1);
#pragma unroll
            for (int nt = 0; nt < 4; ++nt) {
                int c = nt * 16 + lr;
                float2 f = ((const float2*)freqs)[(size_t)tt * 32 + (c >> 1)];
                float sgn = (c & 1) ? f.y : -f.y;
                float qe = acc[nt][r];
                float qp = __shfl_xor(qe, 1);
                q[(size_t)t * DK + c] = f2bf(qe * f.x + qp * sgn);
                float ke = acc[nt + 4][r];
                float kp = __shfl_xor(ke, 1);
                k[(size_t)t * DK + c] = f2bf(ke * f.x + kp * sgn);
                vs[wq * 16 + lg * 4 + r][c] = f2bf(acc[nt + 8][r]);
            }
        }
    }
    __syncthreads();
    // transposed V write, coalesced bf16x8 along t
    int b   = blockIdx.x >> 6;
    int tt0 = (blockIdx.x & 63) * 64;
    int c   = threadIdx.x & 63;
    int tg  = threadIdx.x >> 6;
    bf16x8 val;
#pragma unroll
    for (int j = 0; j < 8; ++j) val[j] = vs[tg * 8 + j][c];
    *(bf16x8*)(vt + ((size_t)b * DK + c) * TT + tt0 + tg * 8) = val;
}

// ---------------- Kernel 2: causal flash attention
// grid (64, B, 4 splits) x 256 threads. Block: q-tile 64 rows (4 waves x 16),
// kv tiles of 64 staged in LDS (XOR-swizzled, double-buffered, reg-staged).
// Split s takes kv tiles {s, s+4, ...}; partials (m,l,o) to workspace.
__global__ __launch_bounds__(256, 3) void attn_kernel(const short* __restrict__ q,
                                                      const short* __restrict__ k,
                                                      const short* __restrict__ vt,
                                                      float* __restrict__ po,
                                                      float* __restrict__ ml)
{
    __shared__ short Kb[2][64][64];     // 16 KB, 16B-unit XOR swizzle
    __shared__ short Vb[2][64][64];     // 16 KB
    __shared__ short pbuf[4][16][72];   // 9 KB

    int w  = threadIdx.x >> 6;
    int l  = threadIdx.x & 63;
    int lr = l & 15;
    int lg = l >> 4;
    int b  = blockIdx.y;
    int s  = blockIdx.z;
    int qt = 63 - blockIdx.x;           // heavy first
    int q0 = qt * 64;
    int qrow_wave = q0 + w * 16;

    const short* qB = q  + (size_t)b * TT * DK;
    const short* kB = k  + (size_t)b * TT * DK;
    const short* vB = vt + (size_t)b * DK * TT;

    bf16x8 qf0 = *(const bf16x8*)(qB + (size_t)(qrow_wave + lr) * DK + 8 * lg);
    bf16x8 qf1 = *(const bf16x8*)(qB + (size_t)(qrow_wave + lr) * DK + 32 + 8 * lg);

    f32x4 of[4];
#pragma unroll
    for (int i = 0; i < 4; ++i) of[i] = (f32x4){0.f, 0.f, 0.f, 0.f};
    float m[4], lsum[4];
#pragma unroll
    for (int r = 0; r < 4; ++r) { m[r] = -INFINITY; lsum[r] = 0.f; }

    int nt = (qt >= s) ? ((qt - s + 4) >> 2) : 0;

    // staging thread-geometry (block-wide, 256 threads cover 64x64 bf16 tile)
    int srow = threadIdx.x >> 2;
    int u0   = (threadIdx.x & 3) * 2;
    int p0s  = ((u0) ^ (srow & 7)) * 8;
    int p1s  = ((u0 + 1) ^ (srow & 7)) * 8;

    bf16x8 kr0, kr1, vr0, vr1;
    short* mypb = &pbuf[w][0][0];

#define ISSUE(tile_) do {                                                        \
        int kv0_ = (tile_) << 6;                                                 \
        const short* gk_ = kB + (size_t)(kv0_ + srow) * DK + (u0 * 8);           \
        const short* gv_ = vB + (size_t)srow * TT + kv0_ + (u0 * 8);             \
        kr0 = *(const bf16x8*)gk_; kr1 = *(const bf16x8*)(gk_ + 8);              \
        vr0 = *(const bf16x8*)gv_; vr1 = *(const bf16x8*)(gv_ + 8);              \
    } while (0)

#define WRITE(buf_) do {                                                         \
        *(bf16x8*)&Kb[buf_][srow][p0s] = kr0;                                    \
        *(bf16x8*)&Kb[buf_][srow][p1s] = kr1;                                    \
        *(bf16x8*)&Vb[buf_][srow][p0s] = vr0;                                    \
        *(bf16x8*)&Vb[buf_][srow][p1s] = vr1;                                    \
    } while (0)

    if (nt > 0) {
        ISSUE(s); WRITE(0);
        if (nt > 1) ISSUE(s + 4);
        __syncthreads();
        int cur = 0;
        for (int i = 0; i < nt; ++i) {
            int kv0 = (s + i * 4) << 6;
            if (i + 1 < nt) WRITE(cur ^ 1);
            if (i + 2 < nt) ISSUE(s + (i + 2) * 4);

            // ---- QK^T: S = Q(16x64) . K(64x64)^T  -> 4 col-blocks of 16
            f32x4 sc[4];
#pragma unroll
            for (int c = 0; c < 4; ++c) sc[c] = (f32x4){0.f, 0.f, 0.f, 0.f};
#pragma unroll
            for (int c = 0; c < 4; ++c) {
                int row = c * 16 + lr;
                bf16x8 kf0 = *(const bf16x8*)&Kb[cur][row][((lg) ^ (row & 7)) * 8];
                bf16x8 kf1 = *(const bf16x8*)&Kb[cur][row][((4 + lg) ^ (row & 7)) * 8];
                sc[c] = __builtin_amdgcn_mfma_f32_16x16x32_bf16(qf0, kf0, sc[c], 0, 0, 0);
                sc[c] = __builtin_amdgcn_mfma_f32_16x16x32_bf16(qf1, kf1, sc[c], 0, 0, 0);
            }
            // ---- online softmax over 64 kv
            float pm[4];
#pragma unroll
            for (int r = 0; r < 4; ++r) {
                int qg = qrow_wave + lg * 4 + r;
#pragma unroll
                for (int c = 0; c < 4; ++c) {
                    float vsc = sc[c][r] * 0.125f;
                    sc[c][r] = (kv0 + c * 16 + lr <= qg) ? vsc : -INFINITY;
                }
                float mx = fmaxf(fmaxf(sc[0][r], sc[1][r]), fmaxf(sc[2][r], sc[3][r]));
                mx = fmaxf(mx, __shfl_xor(mx, 1));
                mx = fmaxf(mx, __shfl_xor(mx, 2));
                mx = fmaxf(mx, __shfl_xor(mx, 4));
                mx = fmaxf(mx, __shfl_xor(mx, 8));
                pm[r] = mx;                        // finite: col kv0 always <= qg
            }
#pragma unroll
            for (int r = 0; r < 4; ++r) {
                float mn = fmaxf(m[r], pm[r]);
                float alpha = __expf(m[r] - mn);
                float p0 = __expf(sc[0][r] - mn);
                float p1 = __expf(sc[1][r] - mn);
                float p2 = __expf(sc[2][r] - mn);
                float p3 = __expf(sc[3][r] - mn);
                float ps = (p0 + p1) + (p2 + p3);
                ps += __shfl_xor(ps, 1);
                ps += __shfl_xor(ps, 2);
                ps += __shfl_xor(ps, 4);
                ps += __shfl_xor(ps, 8);
                lsum[r] = lsum[r] * alpha + ps;
                m[r] = mn;
#pragma unroll
                for (int dt = 0; dt < 4; ++dt) of[dt][r] *= alpha;
                int prow = (lg * 4 + r) * 72;
                mypb[prow + lr]      = f2bf(p0);
                mypb[prow + 16 + lr] = f2bf(p1);
                mypb[prow + 32 + lr] = f2bf(p2);
                mypb[prow + 48 + lr] = f2bf(p3);
            }
            // ---- PV: of += P(16x64) . V(64xDK)  (Vb holds V^T: [d][kv])
#pragma unroll
            for (int ks = 0; ks < 2; ++ks) {
                bf16x8 pa = *(const bf16x8*)(mypb + lr * 72 + ks * 32 + 8 * lg);
#pragma unroll
                for (int dt = 0; dt < 4; ++dt) {
                    int row = dt * 16 + lr;
                    bf16x8 vf = *(const bf16x8*)&Vb[cur][row][((ks * 4 + lg) ^ (row & 7)) * 8];
                    of[dt] = __builtin_amdgcn_mfma_f32_16x16x32_bf16(pa, vf, of[dt], 0, 0, 0);
                }
            }
            __syncthreads();
            cur ^= 1;
        }
    }
#undef ISSUE
#undef WRITE

    // ---- write partials (always, including idle splits: m=-inf, l=0, o=0)
    float* myo  = po + (((size_t)b * 64 + qt) * 4 + s) * 4096;
    float* myml = ml + (((size_t)b * 64 + qt) * 4 + s) * 128;
#pragma unroll
    for (int r = 0; r < 4; ++r) {
        int row = w * 16 + lg * 4 + r;
#pragma unroll
        for (int dt = 0; dt < 4; ++dt) myo[row * 64 + dt * 16 + lr] = of[dt][r];
        if (lr == 0) { myml[row] = m[r]; myml[64 + row] = lsum[r]; }
    }
}

// ---------------- Kernel 3: merge the 4 kv-split partials
__global__ __launch_bounds__(256) void merge_kernel(const float* __restrict__ po,
                                                    const float* __restrict__ ml,
                                                    float* __restrict__ out)
{
    int qt = blockIdx.x;
    int b  = blockIdx.y;
    int row = threadIdx.x >> 2;
    int cg  = threadIdx.x & 3;

    size_t mlbase = ((size_t)b * 64 + qt) * 4 * 128;
    float mm[4], llv[4];
#pragma unroll
    for (int s = 0; s < 4; ++s) {
        mm[s]  = ml[mlbase + s * 128 + row];
        llv[s] = ml[mlbase + s * 128 + 64 + row];
    }
    float M = fmaxf(fmaxf(mm[0], mm[1]), fmaxf(mm[2], mm[3]));
    float e[4], den = 0.f;
#pragma unroll
    for (int s = 0; s < 4; ++s) { e[s] = __expf(mm[s] - M); den += e[s] * llv[s]; }
    float inv = 1.0f / den;

    size_t pbase = ((size_t)b * 64 + qt) * 4 * 4096;
#pragma unroll
    for (int j = 0; j < 4; ++j) {
        int col = cg * 16 + j * 4;
        f32x4 acc = (f32x4){0.f, 0.f, 0.f, 0.f};
#pragma unroll
        for (int s = 0; s < 4; ++s) {
            f32x4 v = *(const f32x4*)(po + pbase + s * 4096 + row * 64 + col);
            acc += e[s] * v;
        }
        acc *= inv;
        *(f32x4*)(out + ((size_t)b * TT + qt * 64 + row) * DK + col) = acc;
    }
}

extern "C" void kernel_launch(void* const* d_in, const int* in_sizes, int n_in,
                              void* d_out, int out_size, void* d_ws, size_t ws_size,
                              hipStream_t stream) {
    const float* x     = (const float*)d_in[0];
    const float* freqs = (const float*)d_in[1];
    const float* Wq    = (const float*)d_in[2];
    const float* Wk    = (const float*)d_in[3];
    const float* Wv    = (const float*)d_in[4];
    float* out = (float*)d_out;

    char* ws = (char*)d_ws;
    short* Wt  = (short*)ws;                          // 384 KB
    short* qb  = (short*)(ws + 393216);               // 2 MB
    short* kb  = (short*)(ws + 2490368);              // 2 MB
    short* vtb = (short*)(ws + 4587520);              // 2 MB
    float* po  = (float*)(ws + 6684672);              // 16 MB partial O
    float* ml  = (float*)(ws + 23461888);             // 512 KB partial m/l

    hipLaunchKernelGGL(wt_kernel, dim3(768), dim3(256), 0, stream, Wq, Wk, Wv, Wt);
    hipLaunchKernelGGL(proj_rope, dim3(256), dim3(512), 0, stream, x, freqs, Wt, qb, kb, vtb);
    hipLaunchKernelGGL(attn_kernel, dim3(64, BB, 4), dim3(256), 0, stream, qb, kb, vtb, po, ml);
    hipLaunchKernelGGL(merge_kernel, dim3(64, BB), dim3(256), 0, stream, po, ml, out);
}

// Round 4
// 84.984 us; speedup vs baseline: 2.2435x; 1.4006x over previous
//
#include <hip/hip_runtime.h>
#include <hip/hip_bf16.h>

#define BB 4
#define TT 4096
#define DM 1024
#define DK 64

using f32x4  = __attribute__((ext_vector_type(4))) float;
using bf16x8 = __attribute__((ext_vector_type(8))) short;

__device__ __forceinline__ short f2bf(float f) {
    __hip_bfloat16 h = __float2bfloat16(f);
    return __builtin_bit_cast(short, h);
}

// ---------------- Kernel 0: pack Wq|Wk|Wv (f32 [1024][64]) -> Wt bf16 [192][1024]
__global__ __launch_bounds__(256) void wt_kernel(const float* __restrict__ Wq,
                                                 const float* __restrict__ Wk,
                                                 const float* __restrict__ Wv,
                                                 short* __restrict__ Wt) {
    int idx = blockIdx.x * 256 + threadIdx.x;
    if (idx >= 192 * 1024) return;
    int n = idx >> 10;
    int m = idx & 1023;
    const float* W = (n < 64) ? Wq : (n < 128) ? Wk : Wv;
    int c = n & 63;
    Wt[idx] = f2bf(W[m * 64 + c]);
}

// ---------------- Kernel 1: QKV projection as LDS-staged GEMM + fused RoPE / V-transpose
// grid: 768 blocks x 256 threads (4 waves). Block = 64 M-rows x 64 N-cols (N-tile = q|k|v).
// K=1024 in BK=64 chunks, double-buffered, reg-staged (T14), XOR-swizzled LDS (T2).
// XCD-bijective remap: the 3 N-tiles of one mt land on the same XCD -> x L2-shared.
__global__ __launch_bounds__(256, 3) void proj_rope(const float* __restrict__ x,
                                                    const float* __restrict__ freqs,
                                                    const short* __restrict__ Wt,
                                                    short* __restrict__ q,
                                                    short* __restrict__ k,
                                                    short* __restrict__ vt)
{
    __shared__ float As[2][4096];    // [64 rows][16 units of 16B], unit-XOR-swizzled
    __shared__ short Bs[2][4096];    // [64 rows][8 units of 16B],  unit-XOR-swizzled

    int t  = threadIdx.x;
    int w  = t >> 6;
    int l  = t & 63;
    int lr = l & 15;
    int lg = (l >> 4) & 3;
    int bx = blockIdx.x;
    int mt = (bx & 7) * 32 + (bx >> 3) / 3;   // M-tile 0..255, trio-per-XCD
    int nh = (bx >> 3) % 3;                   // 0=q, 1=k, 2=v
    int m0 = mt * 64;

    // staging geometry: thread covers A row t>>2, units (t&3)*4..+3 ; B row t>>2, units (t&3)*2..+1
    int arow = t >> 2, au = (t & 3) * 4;
    int brow = t >> 2, bu = (t & 3) * 2;
    const float* gA = x  + (size_t)(m0 + arow) * DM + au * 4;
    const short* gB = Wt + (size_t)(nh * 64 + brow) * DM + bu * 8;
    int aswz = arow & 7, bswz = brow & 7;

    f32x4 ar[4]; bf16x8 br[2];

#define LOADG(c_) do { int kk = (c_) << 6;                     \
        ar[0] = *(const f32x4*)(gA + kk);                      \
        ar[1] = *(const f32x4*)(gA + kk + 4);                  \
        ar[2] = *(const f32x4*)(gA + kk + 8);                  \
        ar[3] = *(const f32x4*)(gA + kk + 12);                 \
        br[0] = *(const bf16x8*)(gB + kk);                     \
        br[1] = *(const bf16x8*)(gB + kk + 8);                 \
    } while (0)

#define WRITELDS(buf_) do {                                                    \
        int sa = arow * 64;                                                    \
        *(f32x4*)&As[buf_][sa + (((au + 0) ^ aswz) << 2)] = ar[0];             \
        *(f32x4*)&As[buf_][sa + (((au + 1) ^ aswz) << 2)] = ar[1];             \
        *(f32x4*)&As[buf_][sa + (((au + 2) ^ aswz) << 2)] = ar[2];             \
        *(f32x4*)&As[buf_][sa + (((au + 3) ^ aswz) << 2)] = ar[3];             \
        int sb = brow * 64;                                                    \
        *(bf16x8*)&Bs[buf_][sb + (((bu + 0) ^ bswz) << 3)] = br[0];            \
        *(bf16x8*)&Bs[buf_][sb + (((bu + 1) ^ bswz) << 3)] = br[1];            \
    } while (0)

    f32x4 acc[4];
#pragma unroll
    for (int i = 0; i < 4; ++i) acc[i] = (f32x4){0.f, 0.f, 0.f, 0.f};

    LOADG(0); WRITELDS(0); LOADG(1);
    __syncthreads();

    int cur = 0;
    int r7 = lr & 7;
    int amrow = (w * 16 + lr) * 64;
    for (int ch = 0; ch < 16; ++ch) {
#pragma unroll
        for (int s = 0; s < 2; ++s) {
            int u0 = s * 8 + lg * 2;
            f32x4 a0 = *(const f32x4*)&As[cur][amrow + (((u0    ) ^ r7) << 2)];
            f32x4 a1 = *(const f32x4*)&As[cur][amrow + (((u0 + 1) ^ r7) << 2)];
            bf16x8 af;
#pragma unroll
            for (int j = 0; j < 4; ++j) { af[j] = f2bf(a0[j]); af[4 + j] = f2bf(a1[j]); }
            int ub = s * 4 + lg;
#pragma unroll
            for (int nt = 0; nt < 4; ++nt) {
                bf16x8 bfr = *(const bf16x8*)&Bs[cur][(nt * 16 + lr) * 64 + ((ub ^ r7) << 3)];
                acc[nt] = __builtin_amdgcn_mfma_f32_16x16x32_bf16(af, bfr, acc[nt], 0, 0, 0);
            }
        }
        if (ch + 1 < 16) {
            WRITELDS(cur ^ 1);
            if (ch + 2 < 16) LOADG(ch + 2);
            __syncthreads();
            cur ^= 1;
        }
    }
#undef LOADG
#undef WRITELDS

    __syncthreads();            // done with LDS; safe to reuse for V-transpose

    if (nh == 2) {
        // V: stage 64x64 bf16 tile, write vt[b][c][t] coalesced
        short* vs = &Bs[0][0];
#pragma unroll
        for (int r = 0; r < 4; ++r)
#pragma unroll
            for (int nt = 0; nt < 4; ++nt)
                vs[(w * 16 + lg * 4 + r) * 64 + nt * 16 + lr] = f2bf(acc[nt][r]);
        __syncthreads();
        int b   = mt >> 6;
        int tt0 = (mt & 63) * 64;
        int c   = t >> 2;
        int toff = (t & 3) * 16;
        bf16x8 v0, v1;
#pragma unroll
        for (int j = 0; j < 8; ++j) {
            v0[j] = vs[(toff + j) * 64 + c];
            v1[j] = vs[(toff + 8 + j) * 64 + c];
        }
        short* dstv = vt + ((size_t)b * DK + c) * TT + tt0 + toff;
        *(bf16x8*)dstv = v0;
        *(bf16x8*)(dstv + 8) = v1;
    } else {
        short* dst = nh ? k : q;
#pragma unroll
        for (int r = 0; r < 4; ++r) {
            int tg = m0 + w * 16 + lg * 4 + r;
            int tt = tg & (TT - 1);
#pragma unroll
            for (int nt = 0; nt < 4; ++nt) {
                int c = nt * 16 + lr;
                float e = acc[nt][r];
                float p = __shfl_xor(e, 1);
                float2 f = ((const float2*)freqs)[(size_t)tt * 32 + (c >> 1)];
                float sgn = (c & 1) ? f.y : -f.y;
                dst[(size_t)tg * DK + c] = f2bf(e * f.x + p * sgn);
            }
        }
    }
}

// ---------------- Kernel 2: causal flash attention (unchanged from R2)
__global__ __launch_bounds__(256, 3) void attn_kernel(const short* __restrict__ q,
                                                      const short* __restrict__ k,
                                                      const short* __restrict__ vt,
                                                      float* __restrict__ po,
                                                      float* __restrict__ ml)
{
    __shared__ short Kb[2][64][64];
    __shared__ short Vb[2][64][64];
    __shared__ short pbuf[4][16][72];

    int w  = threadIdx.x >> 6;
    int l  = threadIdx.x & 63;
    int lr = l & 15;
    int lg = l >> 4;
    int b  = blockIdx.y;
    int s  = blockIdx.z;
    int qt = 63 - blockIdx.x;
    int q0 = qt * 64;
    int qrow_wave = q0 + w * 16;

    const short* qB = q  + (size_t)b * TT * DK;
    const short* kB = k  + (size_t)b * TT * DK;
    const short* vB = vt + (size_t)b * DK * TT;

    bf16x8 qf0 = *(const bf16x8*)(qB + (size_t)(qrow_wave + lr) * DK + 8 * lg);
    bf16x8 qf1 = *(const bf16x8*)(qB + (size_t)(qrow_wave + lr) * DK + 32 + 8 * lg);

    f32x4 of[4];
#pragma unroll
    for (int i = 0; i < 4; ++i) of[i] = (f32x4){0.f, 0.f, 0.f, 0.f};
    float m[4], lsum[4];
#pragma unroll
    for (int r = 0; r < 4; ++r) { m[r] = -INFINITY; lsum[r] = 0.f; }

    int nt = (qt >= s) ? ((qt - s + 4) >> 2) : 0;

    int srow = threadIdx.x >> 2;
    int u0   = (threadIdx.x & 3) * 2;
    int p0s  = ((u0) ^ (srow & 7)) * 8;
    int p1s  = ((u0 + 1) ^ (srow & 7)) * 8;

    bf16x8 kr0, kr1, vr0, vr1;
    short* mypb = &pbuf[w][0][0];

#define ISSUE(tile_) do {                                                        \
        int kv0_ = (tile_) << 6;                                                 \
        const short* gk_ = kB + (size_t)(kv0_ + srow) * DK + (u0 * 8);           \
        const short* gv_ = vB + (size_t)srow * TT + kv0_ + (u0 * 8);             \
        kr0 = *(const bf16x8*)gk_; kr1 = *(const bf16x8*)(gk_ + 8);              \
        vr0 = *(const bf16x8*)gv_; vr1 = *(const bf16x8*)(gv_ + 8);              \
    } while (0)

#define WRITE(buf_) do {                                                         \
        *(bf16x8*)&Kb[buf_][srow][p0s] = kr0;                                    \
        *(bf16x8*)&Kb[buf_][srow][p1s] = kr1;                                    \
        *(bf16x8*)&Vb[buf_][srow][p0s] = vr0;                                    \
        *(bf16x8*)&Vb[buf_][srow][p1s] = vr1;                                    \
    } while (0)

    if (nt > 0) {
        ISSUE(s); WRITE(0);
        if (nt > 1) ISSUE(s + 4);
        __syncthreads();
        int cur = 0;
        for (int i = 0; i < nt; ++i) {
            int kv0 = (s + i * 4) << 6;
            if (i + 1 < nt) WRITE(cur ^ 1);
            if (i + 2 < nt) ISSUE(s + (i + 2) * 4);

            f32x4 sc[4];
#pragma unroll
            for (int c = 0; c < 4; ++c) sc[c] = (f32x4){0.f, 0.f, 0.f, 0.f};
#pragma unroll
            for (int c = 0; c < 4; ++c) {
                int row = c * 16 + lr;
                bf16x8 kf0 = *(const bf16x8*)&Kb[cur][row][((lg) ^ (row & 7)) * 8];
                bf16x8 kf1 = *(const bf16x8*)&Kb[cur][row][((4 + lg) ^ (row & 7)) * 8];
                sc[c] = __builtin_amdgcn_mfma_f32_16x16x32_bf16(qf0, kf0, sc[c], 0, 0, 0);
                sc[c] = __builtin_amdgcn_mfma_f32_16x16x32_bf16(qf1, kf1, sc[c], 0, 0, 0);
            }
            float pm[4];
#pragma unroll
            for (int r = 0; r < 4; ++r) {
                int qg = qrow_wave + lg * 4 + r;
#pragma unroll
                for (int c = 0; c < 4; ++c) {
                    float vsc = sc[c][r] * 0.125f;
                    sc[c][r] = (kv0 + c * 16 + lr <= qg) ? vsc : -INFINITY;
                }
                float mx = fmaxf(fmaxf(sc[0][r], sc[1][r]), fmaxf(sc[2][r], sc[3][r]));
                mx = fmaxf(mx, __shfl_xor(mx, 1));
                mx = fmaxf(mx, __shfl_xor(mx, 2));
                mx = fmaxf(mx, __shfl_xor(mx, 4));
                mx = fmaxf(mx, __shfl_xor(mx, 8));
                pm[r] = mx;
            }
#pragma unroll
            for (int r = 0; r < 4; ++r) {
                float mn = fmaxf(m[r], pm[r]);
                float alpha = __expf(m[r] - mn);
                float p0 = __expf(sc[0][r] - mn);
                float p1 = __expf(sc[1][r] - mn);
                float p2 = __expf(sc[2][r] - mn);
                float p3 = __expf(sc[3][r] - mn);
                float ps = (p0 + p1) + (p2 + p3);
                ps += __shfl_xor(ps, 1);
                ps += __shfl_xor(ps, 2);
                ps += __shfl_xor(ps, 4);
                ps += __shfl_xor(ps, 8);
                lsum[r] = lsum[r] * alpha + ps;
                m[r] = mn;
#pragma unroll
                for (int dt = 0; dt < 4; ++dt) of[dt][r] *= alpha;
                int prow = (lg * 4 + r) * 72;
                mypb[prow + lr]      = f2bf(p0);
                mypb[prow + 16 + lr] = f2bf(p1);
                mypb[prow + 32 + lr] = f2bf(p2);
                mypb[prow + 48 + lr] = f2bf(p3);
            }
#pragma unroll
            for (int ks = 0; ks < 2; ++ks) {
                bf16x8 pa = *(const bf16x8*)(mypb + lr * 72 + ks * 32 + 8 * lg);
#pragma unroll
                for (int dt = 0; dt < 4; ++dt) {
                    int row = dt * 16 + lr;
                    bf16x8 vf = *(const bf16x8*)&Vb[cur][row][((ks * 4 + lg) ^ (row & 7)) * 8];
                    of[dt] = __builtin_amdgcn_mfma_f32_16x16x32_bf16(pa, vf, of[dt], 0, 0, 0);
                }
            }
            __syncthreads();
            cur ^= 1;
        }
    }
#undef ISSUE
#undef WRITE

    float* myo  = po + (((size_t)b * 64 + qt) * 4 + s) * 4096;
    float* myml = ml + (((size_t)b * 64 + qt) * 4 + s) * 128;
#pragma unroll
    for (int r = 0; r < 4; ++r) {
        int row = w * 16 + lg * 4 + r;
#pragma unroll
        for (int dt = 0; dt < 4; ++dt) myo[row * 64 + dt * 16 + lr] = of[dt][r];
        if (lr == 0) { myml[row] = m[r]; myml[64 + row] = lsum[r]; }
    }
}

// ---------------- Kernel 3: merge the 4 kv-split partials (unchanged)
__global__ __launch_bounds__(256) void merge_kernel(const float* __restrict__ po,
                                                    const float* __restrict__ ml,
                                                    float* __restrict__ out)
{
    int qt = blockIdx.x;
    int b  = blockIdx.y;
    int row = threadIdx.x >> 2;
    int cg  = threadIdx.x & 3;

    size_t mlbase = ((size_t)b * 64 + qt) * 4 * 128;
    float mm[4], llv[4];
#pragma unroll
    for (int s = 0; s < 4; ++s) {
        mm[s]  = ml[mlbase + s * 128 + row];
        llv[s] = ml[mlbase + s * 128 + 64 + row];
    }
    float M = fmaxf(fmaxf(mm[0], mm[1]), fmaxf(mm[2], mm[3]));
    float e[4], den = 0.f;
#pragma unroll
    for (int s = 0; s < 4; ++s) { e[s] = __expf(mm[s] - M); den += e[s] * llv[s]; }
    float inv = 1.0f / den;

    size_t pbase = ((size_t)b * 64 + qt) * 4 * 4096;
#pragma unroll
    for (int j = 0; j < 4; ++j) {
        int col = cg * 16 + j * 4;
        f32x4 acc = (f32x4){0.f, 0.f, 0.f, 0.f};
#pragma unroll
        for (int s = 0; s < 4; ++s) {
            f32x4 v = *(const f32x4*)(po + pbase + s * 4096 + row * 64 + col);
            acc += e[s] * v;
        }
        acc *= inv;
        *(f32x4*)(out + ((size_t)b * TT + qt * 64 + row) * DK + col) = acc;
    }
}

extern "C" void kernel_launch(void* const* d_in, const int* in_sizes, int n_in,
                              void* d_out, int out_size, void* d_ws, size_t ws_size,
                              hipStream_t stream) {
    const float* x     = (const float*)d_in[0];
    const float* freqs = (const float*)d_in[1];
    const float* Wq    = (const float*)d_in[2];
    const float* Wk    = (const float*)d_in[3];
    const float* Wv    = (const float*)d_in[4];
    float* out = (float*)d_out;

    char* ws = (char*)d_ws;
    short* Wt  = (short*)ws;                          // 384 KB
    short* qb  = (short*)(ws + 393216);               // 2 MB
    short* kb  = (short*)(ws + 2490368);              // 2 MB
    short* vtb = (short*)(ws + 4587520);              // 2 MB
    float* po  = (float*)(ws + 6684672);              // 16 MB partial O
    float* ml  = (float*)(ws + 23461888);             // 512 KB partial m/l

    hipLaunchKernelGGL(wt_kernel, dim3(768), dim3(256), 0, stream, Wq, Wk, Wv, Wt);
    hipLaunchKernelGGL(proj_rope, dim3(768), dim3(256), 0, stream, x, freqs, Wt, qb, kb, vtb);
    hipLaunchKernelGGL(attn_kernel, dim3(64, BB, 4), dim3(256), 0, stream, qb, kb, vtb, po, ml);
    hipLaunchKernelGGL(merge_kernel, dim3(64, BB), dim3(256), 0, stream, po, ml, out);
}